// Round 1
// baseline (962.675 us; speedup 1.0000x reference)
//
#include <hip/hip_runtime.h>

#define IN_FEATS 256
#define HID 32
#define OUT_FEATS 256
#define NUM_EMBED 54012
#define N_NODES 65536
#define N_EDGES 1048576
#define BATCH 4096

// ---------------------------------------------------------------------------
// K1: tmp[r][c] = sum_k embed[r][k] * W1[k][c]   (54012 x 32)
// Block: 256 threads = 8 rows x 32 cols. W1 staged in LDS (32 KB).
// ---------------------------------------------------------------------------
__global__ void k_embed_w1(const float* __restrict__ embed,
                           const float* __restrict__ W1,
                           float* __restrict__ tmp) {
    __shared__ float w1s[IN_FEATS * HID];
    int tid = threadIdx.x;
    for (int i = tid; i < IN_FEATS * HID; i += 256) w1s[i] = W1[i];
    __syncthreads();

    int col = tid & 31;
    int row = blockIdx.x * 8 + (tid >> 5);
    if (row >= NUM_EMBED) return;

    const float4* erow = (const float4*)(embed + (size_t)row * IN_FEATS);
    float acc = 0.f;
#pragma unroll 8
    for (int k4 = 0; k4 < IN_FEATS / 4; ++k4) {
        float4 e = erow[k4];
        int k = k4 * 4;
        acc += e.x * w1s[(k    ) * HID + col];
        acc += e.y * w1s[(k + 1) * HID + col];
        acc += e.z * w1s[(k + 2) * HID + col];
        acc += e.w * w1s[(k + 3) * HID + col];
    }
    tmp[row * HID + col] = acc;
}

// ---------------------------------------------------------------------------
// K2: feat1[n][:] = tmp[idx[n]][:]   (gather, 65536 x 32, float4 per thread)
// ---------------------------------------------------------------------------
__global__ void k_gather(const float* __restrict__ tmp,
                         const int* __restrict__ idx,
                         float* __restrict__ feat1) {
    int t = blockIdx.x * 256 + threadIdx.x;
    int n = t >> 3;
    int c = (t & 7) * 4;
    if (n >= N_NODES) return;
    int e = idx[n];
    float4 v = *(const float4*)(tmp + (size_t)e * HID + c);
    *(float4*)(feat1 + (size_t)n * HID + c) = v;
}

// ---------------------------------------------------------------------------
// K3/K5: agg[dst[e]][:] += feat[src[e]][:]  (8 threads/edge, float4 each)
// ---------------------------------------------------------------------------
__global__ void k_scatter(const float* __restrict__ feat,
                          const int* __restrict__ src,
                          const int* __restrict__ dst,
                          float* __restrict__ agg) {
    int t = blockIdx.x * 256 + threadIdx.x;
    int e = t >> 3;
    int c = (t & 7) * 4;
    if (e >= N_EDGES) return;
    int s = src[e];
    int d = dst[e];
    float4 v = *(const float4*)(feat + (size_t)s * HID + c);
    float* a = agg + (size_t)d * HID + c;
    atomicAdd(a + 0, v.x);
    atomicAdd(a + 1, v.y);
    atomicAdd(a + 2, v.z);
    atomicAdd(a + 3, v.w);
}

// ---------------------------------------------------------------------------
// K4: agg = relu(agg + b1), elementwise over N_NODES*HID, in place
// ---------------------------------------------------------------------------
__global__ void k_relu_b(float* __restrict__ agg, const float* __restrict__ b1) {
    int t = blockIdx.x * 256 + threadIdx.x;
    if (t >= N_NODES * HID) return;
    float v = agg[t] + b1[t & 31];
    agg[t] = v > 0.f ? v : 0.f;
}

// ---------------------------------------------------------------------------
// K6: fold W2/Wfc/b2/bfc:
//   M1 = W2 @ Wfc[0:256,:]   [32,256]
//   M2 = W2 @ Wfc[256:512,:] [32,256]
//   bias[c] = bfc[c] + sum_j b2[j]*(Wfc[j][c] + Wfc[256+j][c])
// grid = 65 blocks x 256 threads (rows 0-31 -> M1, 32-63 -> M2, 64 -> bias)
// ---------------------------------------------------------------------------
__global__ void k_fold(const float* __restrict__ W2, const float* __restrict__ b2,
                       const float* __restrict__ Wfc, const float* __restrict__ bfc,
                       float* __restrict__ M1, float* __restrict__ M2,
                       float* __restrict__ bias) {
    int c = threadIdx.x;
    int r = blockIdx.x;
    if (r < 32) {
        float acc = 0.f;
        for (int j = 0; j < 256; ++j) acc += W2[r * 256 + j] * Wfc[j * 256 + c];
        M1[r * 256 + c] = acc;
    } else if (r < 64) {
        int k = r - 32;
        float acc = 0.f;
        for (int j = 0; j < 256; ++j) acc += W2[k * 256 + j] * Wfc[(256 + j) * 256 + c];
        M2[k * 256 + c] = acc;
    } else {
        float acc = bfc[c];
        for (int j = 0; j < 256; ++j) acc += b2[j] * (Wfc[j * 256 + c] + Wfc[(256 + j) * 256 + c]);
        bias[c] = acc;
    }
}

// ---------------------------------------------------------------------------
// K7: out[i][c] = relu( sum_k agg2[g1[i]][k]*M1[k][c]
//                     + sum_k agg2[g2[i]][k]*M2[k][c] + bias[c] )
// one block per pair, 256 threads = 256 output cols
// ---------------------------------------------------------------------------
__global__ void k_final(const float* __restrict__ agg2,
                        const int* __restrict__ g1, const int* __restrict__ g2,
                        const float* __restrict__ M1, const float* __restrict__ M2,
                        const float* __restrict__ bias,
                        float* __restrict__ out) {
    __shared__ float a1s[HID];
    __shared__ float a2s[HID];
    int i = blockIdx.x;
    int c = threadIdx.x;
    if (c < 32) a1s[c] = agg2[(size_t)g1[i] * HID + c];
    else if (c < 64) a2s[c - 32] = agg2[(size_t)g2[i] * HID + (c - 32)];
    __syncthreads();

    float acc = bias[c];
#pragma unroll
    for (int k = 0; k < HID; ++k) {
        acc += a1s[k] * M1[k * 256 + c];
        acc += a2s[k] * M2[k * 256 + c];
    }
    out[(size_t)i * 256 + c] = fmaxf(acc, 0.f);
}

// ---------------------------------------------------------------------------
extern "C" void kernel_launch(void* const* d_in, const int* in_sizes, int n_in,
                              void* d_out, int out_size, void* d_ws, size_t ws_size,
                              hipStream_t stream) {
    const int*   idx   = (const int*)d_in[0];
    const int*   src   = (const int*)d_in[1];
    const int*   dst   = (const int*)d_in[2];
    const int*   g1    = (const int*)d_in[3];
    const int*   g2    = (const int*)d_in[4];
    const float* embed = (const float*)d_in[5];
    const float* W1    = (const float*)d_in[6];
    const float* b1    = (const float*)d_in[7];
    const float* W2    = (const float*)d_in[8];
    const float* b2    = (const float*)d_in[9];
    const float* Wfc   = (const float*)d_in[10];
    const float* bfc   = (const float*)d_in[11];
    float* out = (float*)d_out;

    float* ws    = (float*)d_ws;
    float* tmp   = ws;                                  // 54012*32
    float* feat1 = tmp   + (size_t)NUM_EMBED * HID;     // 65536*32
    float* agg1  = feat1 + (size_t)N_NODES * HID;       // 65536*32
    float* agg2  = agg1  + (size_t)N_NODES * HID;       // 65536*32
    float* M1    = agg2  + (size_t)N_NODES * HID;       // 32*256
    float* M2    = M1    + 32 * 256;                    // 32*256
    float* bias  = M2    + 32 * 256;                    // 256

    hipMemsetAsync(agg1, 0, (size_t)N_NODES * HID * sizeof(float), stream);
    hipMemsetAsync(agg2, 0, (size_t)N_NODES * HID * sizeof(float), stream);

    k_embed_w1<<<(NUM_EMBED + 7) / 8, 256, 0, stream>>>(embed, W1, tmp);
    k_fold<<<65, 256, 0, stream>>>(W2, b2, Wfc, bfc, M1, M2, bias);
    k_gather<<<(N_NODES * 8) / 256, 256, 0, stream>>>(tmp, idx, feat1);
    k_scatter<<<(N_EDGES * 8) / 256, 256, 0, stream>>>(feat1, src, dst, agg1);
    k_relu_b<<<(N_NODES * HID) / 256, 256, 0, stream>>>(agg1, b1);
    k_scatter<<<(N_EDGES * 8) / 256, 256, 0, stream>>>(agg1, src, dst, agg2);
    k_final<<<BATCH, 256, 0, stream>>>(agg2, g1, g2, M1, M2, bias, out);
}

// Round 2
// 266.143 us; speedup vs baseline: 3.6171x; 3.6171x over previous
//
#include <hip/hip_runtime.h>

#define IN_FEATS 256
#define HID 32
#define OUT_FEATS 256
#define NUM_EMBED 54012
#define N_NODES 65536
#define N_EDGES 1048576
#define BATCH 4096

// ---------------------------------------------------------------------------
// K1: tmp[r][c] = sum_k embed[r][k] * W1[k][c]   (54012 x 32)
// 256 threads = 32 row-groups x 8 col-groups; each thread does 4 rows x 4 cols.
// W1 staged in LDS (32 KB), read as float4 (ds_read_b128), 16 FMA per b128.
// ---------------------------------------------------------------------------
__global__ void k_embed_w1(const float* __restrict__ embed,
                           const float* __restrict__ W1,
                           float* __restrict__ tmp) {
    __shared__ float w1s[IN_FEATS * HID];
    int tid = threadIdx.x;
    for (int i = tid; i < IN_FEATS * HID / 4; i += 256)
        ((float4*)w1s)[i] = ((const float4*)W1)[i];
    __syncthreads();

    int rg = tid >> 3;                    // 0..31
    int cg = tid & 7;                     // 0..7
    int r0 = blockIdx.x * 128 + rg * 4;
    int c0 = cg * 4;

    int ra = min(r0 + 0, NUM_EMBED - 1);
    int rb = min(r0 + 1, NUM_EMBED - 1);
    int rc = min(r0 + 2, NUM_EMBED - 1);
    int rd = min(r0 + 3, NUM_EMBED - 1);
    const float4* E0 = (const float4*)(embed + (size_t)ra * IN_FEATS);
    const float4* E1 = (const float4*)(embed + (size_t)rb * IN_FEATS);
    const float4* E2 = (const float4*)(embed + (size_t)rc * IN_FEATS);
    const float4* E3 = (const float4*)(embed + (size_t)rd * IN_FEATS);

    float4 a0 = {0,0,0,0}, a1 = {0,0,0,0}, a2 = {0,0,0,0}, a3 = {0,0,0,0};

#define FMA4(ACC, S, W) \
    ACC.x += (S) * (W).x; ACC.y += (S) * (W).y; ACC.z += (S) * (W).z; ACC.w += (S) * (W).w;

    for (int k4 = 0; k4 < IN_FEATS / 4; ++k4) {
        float4 e0 = E0[k4], e1 = E1[k4], e2 = E2[k4], e3 = E3[k4];
        const float4* wr = (const float4*)(w1s + (k4 * 4) * HID) + cg;  // stride 8 float4/k
        float4 w;
        w = wr[0];  FMA4(a0, e0.x, w) FMA4(a1, e1.x, w) FMA4(a2, e2.x, w) FMA4(a3, e3.x, w)
        w = wr[8];  FMA4(a0, e0.y, w) FMA4(a1, e1.y, w) FMA4(a2, e2.y, w) FMA4(a3, e3.y, w)
        w = wr[16]; FMA4(a0, e0.z, w) FMA4(a1, e1.z, w) FMA4(a2, e2.z, w) FMA4(a3, e3.z, w)
        w = wr[24]; FMA4(a0, e0.w, w) FMA4(a1, e1.w, w) FMA4(a2, e2.w, w) FMA4(a3, e3.w, w)
    }
#undef FMA4

    if (r0 + 0 < NUM_EMBED) *(float4*)(tmp + (size_t)(r0 + 0) * HID + c0) = a0;
    if (r0 + 1 < NUM_EMBED) *(float4*)(tmp + (size_t)(r0 + 1) * HID + c0) = a1;
    if (r0 + 2 < NUM_EMBED) *(float4*)(tmp + (size_t)(r0 + 2) * HID + c0) = a2;
    if (r0 + 3 < NUM_EMBED) *(float4*)(tmp + (size_t)(r0 + 3) * HID + c0) = a3;
}

// ---------------------------------------------------------------------------
// K2: feat1[n][:] = tmp[idx[n]][:]
// ---------------------------------------------------------------------------
__global__ void k_gather(const float* __restrict__ tmp,
                         const int* __restrict__ idx,
                         float* __restrict__ feat1) {
    int t = blockIdx.x * 256 + threadIdx.x;
    int n = t >> 3;
    int c = (t & 7) * 4;
    if (n >= N_NODES) return;
    int e = idx[n];
    float4 v = *(const float4*)(tmp + (size_t)e * HID + c);
    *(float4*)(feat1 + (size_t)n * HID + c) = v;
}

// ---------------------------------------------------------------------------
// CSR build: degree count -> exclusive scan -> fill (dst-sorted src list)
// ---------------------------------------------------------------------------
__global__ void k_count(const int* __restrict__ dst, int* __restrict__ deg) {
    int e = blockIdx.x * 256 + threadIdx.x;
    if (e >= N_EDGES) return;
    atomicAdd(&deg[dst[e]], 1);
}

__global__ void k_scan1(const int* __restrict__ deg, int* __restrict__ incl,
                        int* __restrict__ bsum) {
    __shared__ int lds[256];
    int b = blockIdx.x, t = threadIdx.x;
    int i = b * 256 + t;
    lds[t] = deg[i];
    __syncthreads();
    for (int off = 1; off < 256; off <<= 1) {
        int x = (t >= off) ? lds[t - off] : 0;
        __syncthreads();
        lds[t] += x;
        __syncthreads();
    }
    incl[i] = lds[t];
    if (t == 255) bsum[b] = lds[255];
}

__global__ void k_scan2(const int* __restrict__ bsum, int* __restrict__ boff) {
    __shared__ int lds[256];
    int t = threadIdx.x;
    int v = bsum[t];
    lds[t] = v;
    __syncthreads();
    for (int off = 1; off < 256; off <<= 1) {
        int x = (t >= off) ? lds[t - off] : 0;
        __syncthreads();
        lds[t] += x;
        __syncthreads();
    }
    boff[t] = lds[t] - v;   // exclusive
}

__global__ void k_scan3(const int* __restrict__ incl, const int* __restrict__ boff,
                        const int* __restrict__ deg,
                        int* __restrict__ rowptr, int* __restrict__ cursor) {
    int i = blockIdx.x * 256 + threadIdx.x;
    int val = incl[i] + boff[blockIdx.x];
    rowptr[i + 1] = val;
    cursor[i] = val - deg[i];
    if (i == 0) rowptr[0] = 0;
}

__global__ void k_fill(const int* __restrict__ src, const int* __restrict__ dst,
                       int* __restrict__ cursor, int* __restrict__ esrc) {
    int e = blockIdx.x * 256 + threadIdx.x;
    if (e >= N_EDGES) return;
    int pos = atomicAdd(&cursor[dst[e]], 1);
    esrc[pos] = src[e];
}

// ---------------------------------------------------------------------------
// SpMM1 (CSR gather): agg1[v][c] = relu(b1[c] + sum_{j in row v} feat1[esrc[j]][c])
// 32 lanes per node; each edge row read is one coalesced 128B access.
// ---------------------------------------------------------------------------
__global__ void k_spmm1(const float* __restrict__ feat1,
                        const int* __restrict__ rowptr, const int* __restrict__ esrc,
                        const float* __restrict__ b1, float* __restrict__ agg1) {
    int t = blockIdx.x * 256 + threadIdx.x;
    int v = t >> 5;
    int c = t & 31;
    if (v >= N_NODES) return;
    int beg = rowptr[v], end = rowptr[v + 1];
    float acc = 0.f;
    for (int j = beg; j < end; ++j) {
        int s = esrc[j];
        acc += feat1[(size_t)s * HID + c];
    }
    acc += b1[c];
    agg1[(size_t)v * HID + c] = fmaxf(acc, 0.f);
}

// ---------------------------------------------------------------------------
// SpMM2, only for the 8192 needed batch slots (g1 then g2):
// pairfeat[slot][c] = sum_{j in row v} agg1[esrc[j]][c],  v = g1/g2[slot]
// ---------------------------------------------------------------------------
__global__ void k_spmm2b(const float* __restrict__ agg1,
                         const int* __restrict__ rowptr, const int* __restrict__ esrc,
                         const int* __restrict__ g1, const int* __restrict__ g2,
                         float* __restrict__ pairfeat) {
    int t = blockIdx.x * 256 + threadIdx.x;
    int slot = t >> 5;
    int c = t & 31;
    if (slot >= 2 * BATCH) return;
    int v = (slot < BATCH) ? g1[slot] : g2[slot - BATCH];
    int beg = rowptr[v], end = rowptr[v + 1];
    float acc = 0.f;
    for (int j = beg; j < end; ++j) {
        int s = esrc[j];
        acc += agg1[(size_t)s * HID + c];
    }
    pairfeat[(size_t)slot * HID + c] = acc;
}

// ---------------------------------------------------------------------------
// K6: fold W2/Wfc/b2/bfc into M1[32,256], M2[32,256], bias[256]
// ---------------------------------------------------------------------------
__global__ void k_fold(const float* __restrict__ W2, const float* __restrict__ b2,
                       const float* __restrict__ Wfc, const float* __restrict__ bfc,
                       float* __restrict__ M1, float* __restrict__ M2,
                       float* __restrict__ bias) {
    int c = threadIdx.x;
    int r = blockIdx.x;
    if (r < 32) {
        float acc = 0.f;
        for (int j = 0; j < 256; ++j) acc += W2[r * 256 + j] * Wfc[j * 256 + c];
        M1[r * 256 + c] = acc;
    } else if (r < 64) {
        int k = r - 32;
        float acc = 0.f;
        for (int j = 0; j < 256; ++j) acc += W2[k * 256 + j] * Wfc[(256 + j) * 256 + c];
        M2[k * 256 + c] = acc;
    } else {
        float acc = bfc[c];
        for (int j = 0; j < 256; ++j) acc += b2[j] * (Wfc[j * 256 + c] + Wfc[(256 + j) * 256 + c]);
        bias[c] = acc;
    }
}

// ---------------------------------------------------------------------------
// K7: out[i][c] = relu(pairfeat[i] @ M1[:,c] + pairfeat[B+i] @ M2[:,c] + bias[c])
// ---------------------------------------------------------------------------
__global__ void k_final(const float* __restrict__ pairfeat,
                        const float* __restrict__ M1, const float* __restrict__ M2,
                        const float* __restrict__ bias,
                        float* __restrict__ out) {
    __shared__ float a1s[HID];
    __shared__ float a2s[HID];
    int i = blockIdx.x;
    int c = threadIdx.x;
    if (c < 32) a1s[c] = pairfeat[(size_t)i * HID + c];
    else if (c < 64) a2s[c - 32] = pairfeat[(size_t)(BATCH + i) * HID + (c - 32)];
    __syncthreads();

    float acc = bias[c];
#pragma unroll
    for (int k = 0; k < HID; ++k) {
        acc += a1s[k] * M1[k * 256 + c];
        acc += a2s[k] * M2[k * 256 + c];
    }
    out[(size_t)i * 256 + c] = fmaxf(acc, 0.f);
}

// ---------------------------------------------------------------------------
extern "C" void kernel_launch(void* const* d_in, const int* in_sizes, int n_in,
                              void* d_out, int out_size, void* d_ws, size_t ws_size,
                              hipStream_t stream) {
    const int*   idx   = (const int*)d_in[0];
    const int*   src   = (const int*)d_in[1];
    const int*   dst   = (const int*)d_in[2];
    const int*   g1    = (const int*)d_in[3];
    const int*   g2    = (const int*)d_in[4];
    const float* embed = (const float*)d_in[5];
    const float* W1    = (const float*)d_in[6];
    const float* b1    = (const float*)d_in[7];
    const float* W2    = (const float*)d_in[8];
    const float* b2    = (const float*)d_in[9];
    const float* Wfc   = (const float*)d_in[10];
    const float* bfc   = (const float*)d_in[11];
    float* out = (float*)d_out;

    char* ws = (char*)d_ws;
    float* tmp      = (float*)ws;                                   ws += (size_t)NUM_EMBED * HID * 4;
    float* feat1    = (float*)ws;                                   ws += (size_t)N_NODES * HID * 4;
    float* agg1     = (float*)ws;                                   ws += (size_t)N_NODES * HID * 4;
    float* pairfeat = (float*)ws;                                   ws += (size_t)2 * BATCH * HID * 4;
    float* M1       = (float*)ws;                                   ws += 32 * 256 * 4;
    float* M2       = (float*)ws;                                   ws += 32 * 256 * 4;
    float* bias     = (float*)ws;                                   ws += 256 * 4;
    int*   deg      = (int*)ws;                                     ws += (size_t)N_NODES * 4;
    int*   incl     = (int*)ws;                                     ws += (size_t)N_NODES * 4;
    int*   rowptr   = (int*)ws;                                     ws += (size_t)(N_NODES + 1) * 4 + 4;
    int*   cursor   = (int*)ws;                                     ws += (size_t)N_NODES * 4;
    int*   esrc     = (int*)ws;                                     ws += (size_t)N_EDGES * 4;
    int*   bsum     = (int*)ws;                                     ws += 256 * 4;
    int*   boff     = (int*)ws;                                     ws += 256 * 4;

    hipMemsetAsync(deg, 0, (size_t)N_NODES * sizeof(int), stream);

    // CSR build
    k_count<<<N_EDGES / 256, 256, 0, stream>>>(dst, deg);
    k_scan1<<<N_NODES / 256, 256, 0, stream>>>(deg, incl, bsum);
    k_scan2<<<1, 256, 0, stream>>>(bsum, boff);
    k_scan3<<<N_NODES / 256, 256, 0, stream>>>(incl, boff, deg, rowptr, cursor);
    k_fill<<<N_EDGES / 256, 256, 0, stream>>>(src, dst, cursor, esrc);

    // dense pipeline
    k_embed_w1<<<(NUM_EMBED + 127) / 128, 256, 0, stream>>>(embed, W1, tmp);
    k_fold<<<65, 256, 0, stream>>>(W2, b2, Wfc, bfc, M1, M2, bias);
    k_gather<<<(N_NODES * 8) / 256, 256, 0, stream>>>(tmp, idx, feat1);

    // SpMMs (gather form, no atomics)
    k_spmm1<<<(N_NODES * 32) / 256, 256, 0, stream>>>(feat1, rowptr, esrc, b1, agg1);
    k_spmm2b<<<(2 * BATCH * 32) / 256, 256, 0, stream>>>(agg1, rowptr, esrc, g1, g2, pairfeat);

    k_final<<<BATCH, 256, 0, stream>>>(pairfeat, M1, M2, bias, out);
}